// Round 3
// baseline (539.018 us; speedup 1.0000x reference)
//
#include <hip/hip_runtime.h>
#include <hip/hip_bf16.h>

typedef __attribute__((ext_vector_type(8))) short short8;
typedef __attribute__((ext_vector_type(4))) short short4v;
typedef __attribute__((ext_vector_type(16))) float floatx16;

#define M_DIM 8192
#define N_DIM 4096
#define K_DIM 4096
#define BM 128
#define BN 128
#define BK 64

#define CAST_BLOCKS 16384   // M*K/8/256
#define DEQ_BLOCKS 4096     // 4 n-rows x quarter-K per block

__device__ __constant__ float NF4_TAB[16] = {
    -1.0f, -0.6961928009986877f, -0.5250730514526367f, -0.39491748809814453f,
    -0.28444138169288635f, -0.18477343022823334f, -0.09105003625154495f, 0.0f,
    0.07958029955625534f, 0.16093020141124725f, 0.24611230194568634f,
    0.33791524171829224f, 0.44070982933044434f, 0.5626170039176941f,
    0.7229568362236023f, 1.0f};

// One launch, two roles by block range:
//  blocks [0, DEQ_BLOCKS):            W_eff = NF4[code]*scale + 2*B@A  (bf16)
//  blocks [DEQ_BLOCKS, +CAST_BLOCKS): x fp32 -> bf16
__global__ __launch_bounds__(256)
void prep_kernel(const float* __restrict__ x, const int* __restrict__ codes,
                 const float* __restrict__ scales, const float* __restrict__ la,
                 const float* __restrict__ lb, short8* __restrict__ xb,
                 short4v* __restrict__ W) {
    if (blockIdx.x >= DEQ_BLOCKS) {
        int g = (blockIdx.x - DEQ_BLOCKS) * blockDim.x + threadIdx.x;
        const float4* xp = (const float4*)(x + (size_t)g * 8);
        float4 v0 = xp[0], v1 = xp[1];
        union { short8 v; __hip_bfloat16 h[8]; } u;
        u.h[0] = __float2bfloat16(v0.x);
        u.h[1] = __float2bfloat16(v0.y);
        u.h[2] = __float2bfloat16(v0.z);
        u.h[3] = __float2bfloat16(v0.w);
        u.h[4] = __float2bfloat16(v1.x);
        u.h[5] = __float2bfloat16(v1.y);
        u.h[6] = __float2bfloat16(v1.z);
        u.h[7] = __float2bfloat16(v1.w);
        xb[g] = u.v;
        return;
    }
    __shared__ float tab[16];
    if (threadIdx.x < 16) tab[threadIdx.x] = NF4_TAB[threadIdx.x];
    __syncthreads();

    const int kb = blockIdx.x & 3;               // quarter of K
    const int n0 = (blockIdx.x >> 2) << 2;       // 4 n-rows per block
    const int k0 = kb * 1024 + threadIdx.x * 4;

    float4 a[16];
#pragma unroll
    for (int r = 0; r < 16; r++)
        a[r] = *(const float4*)(la + (size_t)r * K_DIM + k0);

#pragma unroll
    for (int i = 0; i < 4; i++) {
        const int n = n0 + i;
        int4 c = *(const int4*)(codes + (size_t)n * K_DIM + k0);
        float s = scales[(n << 6) + (k0 >> 6)];
        const float* bp = lb + (n << 4);         // wave-uniform -> s_load
        float acc0 = 0.f, acc1 = 0.f, acc2 = 0.f, acc3 = 0.f;
#pragma unroll
        for (int r = 0; r < 16; r++) {
            float br = bp[r];
            acc0 += br * a[r].x;
            acc1 += br * a[r].y;
            acc2 += br * a[r].z;
            acc3 += br * a[r].w;
        }
        union { short4v v; __hip_bfloat16 h[4]; } u;
        u.h[0] = __float2bfloat16(tab[c.x] * s + 2.0f * acc0);
        u.h[1] = __float2bfloat16(tab[c.y] * s + 2.0f * acc1);
        u.h[2] = __float2bfloat16(tab[c.z] * s + 2.0f * acc2);
        u.h[3] = __float2bfloat16(tab[c.w] * s + 2.0f * acc3);
        W[((size_t)n * K_DIM + k0) >> 2] = u.v;
    }
}

#define GL2LDS(gsrc, ldst)                                                   \
    __builtin_amdgcn_global_load_lds(                                        \
        (const __attribute__((address_space(1))) void*)(gsrc),               \
        (__attribute__((address_space(3))) void*)(ldst), 16, 0, 0)

// C[m][n] = sum_k A[m][k] * B[n][k]   (A,B bf16 row-major; C fp32)
// 128x128 tile, BK=64, 4 waves (2x2), each wave 64x64 via 2x2 mfma 32x32x16.
// 16B-block XOR swizzle on global source addrs (LDS dst of global_load_lds is
// fixed base+lane*16) -> ds_read_b128 fragment reads conflict-free.
__global__ __launch_bounds__(256, 3)
void gemm_bt_kernel(const __hip_bfloat16* __restrict__ A,
                    const __hip_bfloat16* __restrict__ B,
                    float* __restrict__ C) {
    __shared__ __align__(16) __hip_bfloat16 sA[BM * BK];
    __shared__ __align__(16) __hip_bfloat16 sB[BN * BK];
    const int tid = threadIdx.x;
    const int wave = tid >> 6;
    const int lane = tid & 63;
    const int l31 = lane & 31;
    const int half = lane >> 5;          // k-half for A/B frags
    const int wm = wave >> 1;
    const int wn = wave & 1;
    const int bm0 = blockIdx.y * BM;
    const int bn0 = blockIdx.x * BN;

    floatx16 acc[2][2] = {};

    const __hip_bfloat16* ga[4];
    const __hip_bfloat16* gb[4];
#pragma unroll
    for (int i = 0; i < 4; i++) {
        int rt = i * 32 + (tid >> 3);
        int cb = (tid & 7) ^ (rt & 7);
        ga[i] = A + (size_t)(bm0 + rt) * K_DIM + cb * 8;
        gb[i] = B + (size_t)(bn0 + rt) * K_DIM + cb * 8;
    }

    for (int k0 = 0; k0 < K_DIM; k0 += BK) {
#pragma unroll
        for (int i = 0; i < 4; i++) {
            GL2LDS(ga[i] + k0, (char*)sA + (i * 256 + wave * 64) * 16);
            GL2LDS(gb[i] + k0, (char*)sB + (i * 256 + wave * 64) * 16);
        }
        __syncthreads();
#pragma unroll
        for (int ks = 0; ks < BK; ks += 16) {
            short8 af[2], bfr[2];
            const int cb = (ks >> 3) + half;   // frag k = ks + half*8 + j
#pragma unroll
            for (int mi = 0; mi < 2; mi++) {
                int row = wm * 64 + mi * 32 + l31;
                af[mi] = *(const short8*)&sA[row * 64 + ((cb ^ (row & 7)) << 3)];
            }
#pragma unroll
            for (int ni = 0; ni < 2; ni++) {
                int row = wn * 64 + ni * 32 + l31;
                bfr[ni] = *(const short8*)&sB[row * 64 + ((cb ^ (row & 7)) << 3)];
            }
#pragma unroll
            for (int mi = 0; mi < 2; mi++)
#pragma unroll
                for (int ni = 0; ni < 2; ni++)
                    acc[mi][ni] = __builtin_amdgcn_mfma_f32_32x32x16_bf16(
                        af[mi], bfr[ni], acc[mi][ni], 0, 0, 0);
        }
        __syncthreads();
    }

    // C/D layout (m74/m101): col=lane&31, row=(reg&3)+8*(reg>>2)+4*(lane>>5)
#pragma unroll
    for (int mi = 0; mi < 2; mi++) {
        int rbase = bm0 + wm * 64 + mi * 32 + 4 * half;
#pragma unroll
        for (int ni = 0; ni < 2; ni++) {
            int col = bn0 + wn * 64 + ni * 32 + l31;
#pragma unroll
            for (int reg = 0; reg < 16; reg++) {
                int row = rbase + (reg & 3) + 8 * (reg >> 2);
                C[(size_t)row * N_DIM + col] = acc[mi][ni][reg];
            }
        }
    }
}

extern "C" void kernel_launch(void* const* d_in, const int* in_sizes, int n_in,
                              void* d_out, int out_size, void* d_ws,
                              size_t ws_size, hipStream_t stream) {
    const float* x = (const float*)d_in[0];
    const int* codes = (const int*)d_in[1];
    const float* scales = (const float*)d_in[2];
    const float* loraA = (const float*)d_in[3];
    const float* loraB = (const float*)d_in[4];
    float* out = (float*)d_out;

    char* ws = (char*)d_ws;
    __hip_bfloat16* xb = (__hip_bfloat16*)ws;                    // 64 MiB
    __hip_bfloat16* Wb = (__hip_bfloat16*)(ws + 67108864);       // 32 MiB

    prep_kernel<<<dim3(DEQ_BLOCKS + CAST_BLOCKS), dim3(256), 0, stream>>>(
        x, codes, scales, loraA, loraB, (short8*)xb, (short4v*)Wb);
    gemm_bt_kernel<<<dim3(N_DIM / BN, M_DIM / BM), dim3(256), 0, stream>>>(
        xb, Wb, out);
}